// Round 3
// baseline (8811.868 us; speedup 1.0000x reference)
//
#include <hip/hip_runtime.h>
#include <stdint.h>

// SpatialGRU on MI355X, round 5: persistent kernel + private x pre-transpose.
// Round-4 post-mortem: VGPR_Count=64 -> launch_bounds(1024) caps 128 unified
// regs/wave (64 = acc AGPRs), so all "register hoists" were remat'd. FETCH
// 797KB/block-step == weight stream re-pulled from LLC every step; cause is
// L2 thrash from x staging overfetch (2048 x 4B loads @ 25.6KB stride = 256KB
// lines/block-step). Fix: per-block one-time transpose of its x column into
// contiguous bf16 xp (320KB/block in ws, runtime ws_size check + fallback);
// per-step x = one 4KB nt read. L2 set drops to weights+scratch ~2.9MB < 4MB
// -> weights L2-resident. Fake hoists removed. Protocol unchanged.

typedef __bf16 bf16x8 __attribute__((ext_vector_type(8)));
typedef float  f32x4  __attribute__((ext_vector_type(4)));
typedef unsigned short ushort4v __attribute__((ext_vector_type(4)));
typedef unsigned short ushort2v __attribute__((ext_vector_type(2)));

#define QPITCH 424   // 416 q cols + 8 pad (bf16 elems)
#define HPITCH 132   // fp32 h rows padded +4

__device__ int g_progress[160];   // cells completed per block

__device__ __forceinline__ unsigned short f2bf(float x) {
  unsigned int u = __builtin_bit_cast(unsigned int, x);
  u = u + 0x7FFFu + ((u >> 16) & 1u);          // round-to-nearest-even
  return (unsigned short)(u >> 16);
}
__device__ __forceinline__ float bf2f(unsigned short h) {
  unsigned int u = ((unsigned int)h) << 16;
  return __builtin_bit_cast(float, u);
}
__device__ __forceinline__ float sigm(float x) {
  x = fminf(fmaxf(x, -30.f), 30.f);
  return 1.f / (1.f + __expf(-x));
}
__device__ __forceinline__ float tanh_fast(float x) {
  x = fminf(fmaxf(x, -15.f), 15.f);
  float e = __expf(2.f * x);
  return (e - 1.f) / (e + 1.f);
}

// LLC-coherent (L2-bypass) 32B load / 16B store for the cross-XCD ring.
__device__ __forceinline__ void llc_load32(const float* p, f32x4& a, f32x4& b) {
  asm volatile("global_load_dwordx4 %0, %2, off sc0 sc1\n\t"
               "global_load_dwordx4 %1, %3, off sc0 sc1\n\t"
               "s_waitcnt vmcnt(0)"
               : "=&v"(a), "=&v"(b)
               : "v"(p), "v"(p + 4)
               : "memory");
}
__device__ __forceinline__ void llc_store16(float* p, f32x4 v) {
  asm volatile("global_store_dwordx4 %0, %1, off sc0 sc1"
               :: "v"(p), "v"(v) : "memory");
}

// ---------------------------------------------------------------------------
// prep: pack fused W' (1024 x 416) and WU' (128 x 384) into MFMA A-fragment
// order (unchanged) + zero the progress flags.
// ---------------------------------------------------------------------------
__global__ void prep_kernel(const float* __restrict__ Wr, const float* __restrict__ Wz,
                            const float* __restrict__ Wij, const float* __restrict__ WU,
                            const float* __restrict__ br, const float* __restrict__ bz,
                            const float* __restrict__ bij,
                            unsigned short* __restrict__ wp1, unsigned short* __restrict__ wp2,
                            float* __restrict__ bfused) {
  int blk = blockIdx.x, lane = threadIdx.x;
  if (blk < 832) {                       // 13 kb * 64 ntiles for W'
    int kb = blk >> 6, nt = blk & 63;
    int n = nt * 16 + (lane & 15);
    int kb8 = kb * 32 + (lane >> 4) * 8;
    unsigned short v[8];
#pragma unroll
    for (int j = 0; j < 8; ++j) {
      int k = kb8 + j; float w;
      if (n < 384) w = Wr[n * 416 + k];
      else if (n < 896) { int u = (n - 384) >> 2, g = (n - 384) & 3; w = Wz[(g * 128 + u) * 416 + k]; }
      else { int u = n - 896; w = (k >= 384) ? Wij[u * 32 + (k - 384)] : 0.f; }
      v[j] = f2bf(w);
    }
    ushort4v* dst = (ushort4v*)(wp1 + ((size_t)(kb * 64 + nt) * 64 + lane) * 8);
    dst[0] = (ushort4v){v[0], v[1], v[2], v[3]};
    dst[1] = (ushort4v){v[4], v[5], v[6], v[7]};
  } else if (blk < 832 + 96) {           // 12 kb * 8 ntiles for WU'
    int b2 = blk - 832;
    int kb = b2 >> 3, nt = b2 & 7;
    int n = nt * 16 + (lane & 15);
    int kb8 = kb * 32 + (lane >> 4) * 8;
    unsigned short v[8];
#pragma unroll
    for (int j = 0; j < 8; ++j) {
      int c = kb8 + j;
      int s = (c < 128) ? c + 128 : (c < 256 ? c - 128 : c);  // block swap
      v[j] = f2bf(WU[n * 384 + s]);
    }
    ushort4v* dst = (ushort4v*)(wp2 + ((size_t)(kb * 8 + nt) * 64 + lane) * 8);
    dst[0] = (ushort4v){v[0], v[1], v[2], v[3]};
    dst[1] = (ushort4v){v[4], v[5], v[6], v[7]};
  } else if (blk == 928) {               // fused bias (1024 fp32)
#pragma unroll
    for (int i = 0; i < 16; ++i) {
      int n = lane * 16 + i; float v;
      if (n < 384) v = br[n];
      else if (n < 896) { int u = (n - 384) >> 2, g = (n - 384) & 3; v = bz[g * 128 + u]; }
      else v = bij[n - 896];
      bfused[n] = v;
    }
  } else {                               // zero progress flags
    for (int i = lane; i < 160; i += 64)
      __hip_atomic_store(&g_progress[i], 0, __ATOMIC_RELAXED, __HIP_MEMORY_SCOPE_AGENT);
  }
}

// one GEMM1 K-step (16 MFMA over the wave's 64n x 64b tile), weights from L2
#define G1_STEP(KB)                                                                        \
  {                                                                                        \
    bf16x8 wf[4], qf[4];                                                                   \
    _Pragma("unroll")                                                                      \
    for (int mt = 0; mt < 4; ++mt)                                                         \
      wf[mt] = *(const bf16x8*)(wp1 + ((size_t)((KB) * 64 + ntb + mt) * 64 + lane) * 8);   \
    _Pragma("unroll")                                                                      \
    for (int bt = 0; bt < 4; ++bt)                                                         \
      qf[bt] = *(const bf16x8*)(lds + (size_t)(bt * 16 + l15) * QPITCH + (KB) * 32 + quad * 8); \
    _Pragma("unroll")                                                                      \
    for (int mt = 0; mt < 4; ++mt)                                                         \
      _Pragma("unroll")                                                                    \
      for (int bt = 0; bt < 4; ++bt)                                                       \
        acc[mt][bt] = __builtin_amdgcn_mfma_f32_16x16x32_bf16(wf[mt], qf[bt], acc[mt][bt], 0, 0, 0); \
  }

// ---------------------------------------------------------------------------
// Persistent wavefront kernel. LDS layout (155,648 B):
//   q bf16 [64][QPITCH]              @ 0       (54,272 B)  cols: ht|hl|hd|x
//   htopF fp32 [64][HPITCH]          @ 54,272  (33,792 B)  own h(l-1)
//   hlD0/hlD1 fp32 [64][HPITCH]      @ 88,064 / 121,856    h_left double buf
// ---------------------------------------------------------------------------
__global__ __launch_bounds__(1024)
void gru_persist(const float* __restrict__ x, const float* __restrict__ bfused,
                 const unsigned short* __restrict__ wp1, const unsigned short* __restrict__ wp2,
                 float* __restrict__ ring, float* __restrict__ scratch,
                 unsigned short* __restrict__ xp,   // nullable: 160 x [80][2048] bf16
                 float* __restrict__ out) {
  const int blk = blockIdx.x;
  const int rc = (blk < 80) ? blk : blk - 80;
  const int bh = (blk < 80) ? 0 : 1;
  const int tid = threadIdx.x;
  const int wave = tid >> 6, lane = tid & 63;
  const int quad = lane >> 4, l15 = lane & 15;
  const int i2 = tid * 2;                        // (b_local, c) pair id
  const int bb = i2 >> 5, cc = i2 & 31;

  extern __shared__ char smem[];
  unsigned short* lds = (unsigned short*)smem;
  float* htopF = (float*)(smem + 54272);
  float* hlD0  = (float*)(smem + 88064);
  float* hlD1  = (float*)(smem + 121856);

  float* scr  = scratch + (size_t)blk * 24576;  // per-block, own-XCD L2
  float* hz_s = scr;
  float* zi_s = scr + 8192;
  float* cw_s = scr + 16384;
  float* ringMine = ring + (size_t)blk * 24576;  // 3 slots x 8192 fp32
  unsigned short* xpB = xp ? (xp + (size_t)blk * 163840) : nullptr;

  // ---- init: zero h buffers + q cols 0..383 ----
  for (int i = tid; i < 64 * HPITCH; i += 1024) { htopF[i] = 0.f; hlD0[i] = 0.f; hlD1[i] = 0.f; }
  {
    int r = tid >> 4, c0 = (tid & 15) * 24;      // 64 rows x 384 cols
#pragma unroll
    for (int j = 0; j < 6; ++j)
      *(ushort4v*)(lds + (size_t)r * QPITCH + c0 + j * 4) = (ushort4v){0, 0, 0, 0};
  }
  // ---- x path: one-time private transpose (contiguous bf16 per l) ----
  if (xpB) {
    const float* xb = x + (size_t)(bh * 2048 + i2) * 6400 + rc;
#pragma unroll 4
    for (int l = 0; l < 80; ++l) {
      float v0 = __builtin_nontemporal_load(xb + l * 80);
      float v1 = __builtin_nontemporal_load(xb + 6400 + l * 80);
      ushort2v o = (ushort2v){f2bf(v0), f2bf(v1)};
      __builtin_nontemporal_store(__builtin_bit_cast(unsigned int, o),
                                  (unsigned int*)(xpB + (size_t)l * 2048 + i2));
      if (l == 0)
        *(ushort2v*)(lds + (size_t)bb * QPITCH + 384 + cc) = o;   // stage l=0 now
    }
  } else {
    const float* xb = x + rc;                    // fallback: direct strided
    float v0 = __builtin_nontemporal_load(xb + (size_t)(bh * 2048 + i2) * 6400);
    float v1 = __builtin_nontemporal_load(xb + (size_t)(bh * 2048 + i2 + 1) * 6400);
    *(ushort2v*)(lds + (size_t)bb * QPITCH + 384 + cc) = (ushort2v){f2bf(v0), f2bf(v1)};
  }
  __syncthreads();                               // drains xp stores too

  const int ntb = wave * 4;
  const int m2 = wave >> 1, bsel = wave & 1;

  for (int l = 0; l < 80; ++l) {
    // ---- x tile prefetch for l+1 (nt: no L2 alloc; hidden under part A) ----
    unsigned int xn = 0;
    if (l < 79) {
      if (xpB) {
        xn = __builtin_nontemporal_load((const unsigned int*)(xpB + (size_t)(l + 1) * 2048 + i2));
      } else {
        const float* xb = x + (size_t)(l + 1) * 80 + rc;
        float v0 = __builtin_nontemporal_load(xb + (size_t)(bh * 2048 + i2) * 6400);
        float v1 = __builtin_nontemporal_load(xb + (size_t)(bh * 2048 + i2 + 1) * 6400);
        xn = __builtin_bit_cast(unsigned int, (ushort2v){f2bf(v0), f2bf(v1)});
      }
    }

    // ---- GEMM1 part A: kb {0..3, 8..12} (ht, hd, x) — neighbor-free ----
    f32x4 acc[4][4];
#pragma unroll
    for (int mt = 0; mt < 4; ++mt)
#pragma unroll
      for (int bt = 0; bt < 4; ++bt) acc[mt][bt] = (f32x4){0.f, 0.f, 0.f, 0.f};
#pragma unroll
    for (int t = 0; t < 9; ++t) {
      const int kb = (t < 4) ? t : t + 4;
      G1_STEP(kb)
    }

    // ---- spin (single lane): left done row l; right consumed slot ----
    if (tid == 0) {
      if (rc > 0)
        while (__hip_atomic_load(&g_progress[blk - 1], __ATOMIC_RELAXED, __HIP_MEMORY_SCOPE_AGENT) < l + 1)
          __builtin_amdgcn_s_sleep(1);
      if (rc < 79)
        while (__hip_atomic_load(&g_progress[blk + 1], __ATOMIC_RELAXED, __HIP_MEMORY_SCOPE_AGENT) < l - 2)
          __builtin_amdgcn_s_sleep(1);
    }
    asm volatile("" ::: "memory");
    __syncthreads();                                             // B1

    // ---- stage B: h_left from neighbor ring (LLC dwordx4) ----
    if (rc > 0) {
      const float* src = ring + (size_t)(blk - 1) * 24576 + (size_t)(l % 3) * 8192 + tid * 8;
      f32x4 a, b;
      llc_load32(src, a, b);
      int bl = (tid * 8) >> 7, u = (tid * 8) & 127;
      float* hlF = (l & 1) ? hlD1 : hlD0;
      *(f32x4*)(hlF + bl * HPITCH + u)     = a;
      *(f32x4*)(hlF + bl * HPITCH + u + 4) = b;
      *(ushort4v*)(lds + (size_t)bl * QPITCH + 128 + u)     = (ushort4v){f2bf(a[0]), f2bf(a[1]), f2bf(a[2]), f2bf(a[3])};
      *(ushort4v*)(lds + (size_t)bl * QPITCH + 128 + u + 4) = (ushort4v){f2bf(b[0]), f2bf(b[1]), f2bf(b[2]), f2bf(b[3])};
    }
    // rc==0: hl columns stay zero forever
    __syncthreads();                                             // B2

    // ---- GEMM1 part B: kb 4..7 (hl) ----
#pragma unroll
    for (int kb = 4; kb < 8; ++kb) { G1_STEP(kb) }
    __syncthreads();                                             // B3

    // ---- elementwise ----
    if (wave < 6) {
      // r class: sigmoid, A2' = r*q in place (shift maps r col -> q col)
      const int rn0 = wave * 64;
      const int shift = (rn0 < 128) ? 128 : (rn0 < 256 ? -128 : 0);
#pragma unroll
      for (int mt = 0; mt < 4; ++mt)
#pragma unroll
        for (int bt = 0; bt < 4; ++bt) {
          int n0 = rn0 + mt * 16 + quad * 4;
          int row = bt * 16 + l15;
          unsigned short* p = lds + (size_t)row * QPITCH + n0 + shift;
          ushort4v qv = *(ushort4v*)p;
          ushort4v o;
#pragma unroll
          for (int g = 0; g < 4; ++g) {
            float r = sigm(acc[mt][bt][g] + bfused[n0 + g]);
            o[g] = f2bf(bf2f(qv[g]) * r);
          }
          *(ushort4v*)p = o;
        }
    } else if (wave < 14) {
      // z class: lane-local softmax over 4 gates; fold fp32 h's from LDS
      const float* hlF = (l & 1) ? hlD1 : hlD0;
      const float* hdF = (l & 1) ? hlD0 : hlD1;
#pragma unroll
      for (int mt = 0; mt < 4; ++mt)
#pragma unroll
        for (int bt = 0; bt < 4; ++bt) {
          int nb = wave * 64 + mt * 16 + quad * 4;
          int u = (nb - 384) >> 2;
          int bl = bt * 16 + l15;
          float v0 = acc[mt][bt][0] + bfused[nb];
          float v1 = acc[mt][bt][1] + bfused[nb + 1];
          float v2 = acc[mt][bt][2] + bfused[nb + 2];
          float v3 = acc[mt][bt][3] + bfused[nb + 3];
          float m = fmaxf(fmaxf(v0, v1), fmaxf(v2, v3));
          float e0 = __expf(v0 - m), e1 = __expf(v1 - m);
          float e2 = __expf(v2 - m), e3 = __expf(v3 - m);
          float inv = 1.f / (e0 + e1 + e2 + e3);
          float hl = hlF[bl * HPITCH + u];
          float ht = htopF[bl * HPITCH + u];
          float hd = hdF[bl * HPITCH + u];
          hz_s[bl * 128 + u] = (e1 * hl + e2 * ht + e3 * hd) * inv;  // zl,zt,zd
          zi_s[bl * 128 + u] = e0 * inv;
        }
    } else {
      // wij class: cw = acc + bij
#pragma unroll
      for (int mt = 0; mt < 4; ++mt)
#pragma unroll
        for (int bt = 0; bt < 4; ++bt) {
          int n0 = wave * 64 + mt * 16 + quad * 4;
          int uw = n0 - 896;
          int bl = bt * 16 + l15;
          f32x4 o;
#pragma unroll
          for (int g = 0; g < 4; ++g) o[g] = acc[mt][bt][g] + bfused[n0 + g];
          *(f32x4*)(cw_s + bl * 128 + uw) = o;
        }
    }
    __syncthreads();                                             // B4

    // ---- GEMM2: hU^T = WU' @ A2'^T (M=128 u, K=384, N=64 bl) ----
    f32x4 acc2[2];
    acc2[0] = (f32x4){0.f, 0.f, 0.f, 0.f};
    acc2[1] = (f32x4){0.f, 0.f, 0.f, 0.f};
#pragma unroll
    for (int kb = 0; kb < 12; ++kb) {
      bf16x8 wf = *(const bf16x8*)(wp2 + ((size_t)(kb * 8 + m2) * 64 + lane) * 8);
      bf16x8 q0 = *(const bf16x8*)(lds + (size_t)((bsel * 2 + 0) * 16 + l15) * QPITCH + kb * 32 + quad * 8);
      bf16x8 q1 = *(const bf16x8*)(lds + (size_t)((bsel * 2 + 1) * 16 + l15) * QPITCH + kb * 32 + quad * 8);
      acc2[0] = __builtin_amdgcn_mfma_f32_16x16x32_bf16(wf, q0, acc2[0], 0, 0, 0);
      acc2[1] = __builtin_amdgcn_mfma_f32_16x16x32_bf16(wf, q1, acc2[1], 0, 0, 0);
    }
    __syncthreads();                                             // B5

    // ---- combine: h = hz + zi*tanh(cw + hU); publish + local copies ----
#pragma unroll
    for (int bt = 0; bt < 2; ++bt) {
      int bl = (bsel * 2 + bt) * 16 + l15;
      int u0 = m2 * 16 + quad * 4;
      f32x4 cw = *(f32x4*)(cw_s + bl * 128 + u0);
      f32x4 hz = *(f32x4*)(hz_s + bl * 128 + u0);
      f32x4 zi = *(f32x4*)(zi_s + bl * 128 + u0);
      f32x4 h;
#pragma unroll
      for (int g = 0; g < 4; ++g)
        h[g] = hz[g] + zi[g] * tanh_fast(cw[g] + acc2[bt][g]);
      llc_store16(ringMine + (size_t)(l % 3) * 8192 + bl * 128 + u0, h);
      *(f32x4*)(htopF + bl * HPITCH + u0) = h;                    // next ht fp32
      *(ushort4v*)(lds + (size_t)bl * QPITCH + u0) =              // next ht bf16
          (ushort4v){f2bf(h[0]), f2bf(h[1]), f2bf(h[2]), f2bf(h[3])};
      if (rc == 79 && l == 79)
        *(f32x4*)(out + (size_t)(bh * 64 + bl) * 128 + u0) = h;
    }
    // ---- stage A for l+1 (hd <- this step's hl fp32; x from prefetch) ----
    if (l < 79) {
      const float* hdF = ((l + 1) & 1) ? hlD0 : hlD1;
      int idx = tid * 8, bl = idx >> 7, u = idx & 127;
      f32x4 a = *(const f32x4*)(hdF + bl * HPITCH + u);
      f32x4 b = *(const f32x4*)(hdF + bl * HPITCH + u + 4);
      *(ushort4v*)(lds + (size_t)bl * QPITCH + 256 + u)     = (ushort4v){f2bf(a[0]), f2bf(a[1]), f2bf(a[2]), f2bf(a[3])};
      *(ushort4v*)(lds + (size_t)bl * QPITCH + 256 + u + 4) = (ushort4v){f2bf(b[0]), f2bf(b[1]), f2bf(b[2]), f2bf(b[3])};
      *(ushort2v*)(lds + (size_t)bb * QPITCH + 384 + cc) = __builtin_bit_cast(ushort2v, xn);
    }
    __syncthreads();                                             // B6 (drains ring stores)
    if (tid == 0)
      __hip_atomic_store(&g_progress[blk], l + 1, __ATOMIC_RELAXED, __HIP_MEMORY_SCOPE_AGENT);
  }
}

// ---------------------------------------------------------------------------
extern "C" void kernel_launch(void* const* d_in, const int* in_sizes, int n_in,
                              void* d_out, int out_size, void* d_ws, size_t ws_size,
                              hipStream_t stream) {
  const float* x   = (const float*)d_in[0];
  const float* Wr  = (const float*)d_in[1];
  const float* br  = (const float*)d_in[2];
  const float* Wz  = (const float*)d_in[3];
  const float* bz  = (const float*)d_in[4];
  const float* Wij = (const float*)d_in[5];
  const float* bij = (const float*)d_in[6];
  const float* WU  = (const float*)d_in[7];
  float* out = (float*)d_out;

  // ws layout: wp1 | wp2 | bfused | ring | scratch | xp
  char* ws = (char*)d_ws;
  unsigned short* wp1 = (unsigned short*)(ws);                 //    851,968 B
  unsigned short* wp2 = (unsigned short*)(ws + 851968);        //     98,304 B
  float* bfused       = (float*)(ws + 950272);                 //      4,096 B
  float* ring         = (float*)(ws + 954368);                 // 15,728,640 B
  float* scratch      = (float*)(ws + 16683008);               // 15,728,640 B
  // xp: 160 blocks x 80 l x 2048 bf16 = 52,428,800 B (only if ws allows)
  unsigned short* xp  = (ws_size >= 84840448ull)
                        ? (unsigned short*)(ws + 32411648) : nullptr;

  (void)hipFuncSetAttribute((const void*)gru_persist,
                            hipFuncAttributeMaxDynamicSharedMemorySize, 155648);

  prep_kernel<<<930, 64, 0, stream>>>(Wr, Wz, Wij, WU, br, bz, bij, wp1, wp2, bfused);
  gru_persist<<<160, 1024, 155648, stream>>>(x, bfused, wp1, wp2, ring, scratch, xp, out);
}

// Round 5
// 6542.272 us; speedup vs baseline: 1.3469x; 1.3469x over previous
//
#include <hip/hip_runtime.h>
#include <stdint.h>

// SpatialGRU on MI355X, round 7: round-6 structure + hang-diagnosis hardening.
// Round-6 design (unmeasured: container died twice, cause unknown):
//   (1) Wij folded into GEMM2 as 13th K-block (x cols 384..415) -> cw scratch
//       + wij waves gone, wp1 shrinks to n<896;
//   (2) GEMM2 done by the 8 z-waves with row-permuted wp2 (WU row 4(f&3)+(f>>2)
//       at frag slot f) so hU lands on the same (u,bl) lanes holding hz/zi ->
//       combine fully in-register; global scratch ELIMINATED;
//   (3) ring publish via LDS relay (coalesced dwordx4 sc0 sc1 after barrier).
// Hardening this round: both spin loops get a bounded guard (~45ms per wait,
// legit waits are microseconds) so any protocol wedge self-terminates into a
// failing-but-profiled run instead of killing the container.

typedef __bf16 bf16x8 __attribute__((ext_vector_type(8)));
typedef float  f32x4  __attribute__((ext_vector_type(4)));
typedef unsigned short ushort4v __attribute__((ext_vector_type(4)));
typedef unsigned short ushort2v __attribute__((ext_vector_type(2)));

#define QPITCH 424   // 416 q cols + 8 pad (bf16 elems)
#define HPITCH 132   // fp32 h rows padded +4

__device__ int g_progress[160];   // cells completed per block

__device__ __forceinline__ unsigned short f2bf(float x) {
  unsigned int u = __builtin_bit_cast(unsigned int, x);
  u = u + 0x7FFFu + ((u >> 16) & 1u);          // round-to-nearest-even
  return (unsigned short)(u >> 16);
}
__device__ __forceinline__ float bf2f(unsigned short h) {
  unsigned int u = ((unsigned int)h) << 16;
  return __builtin_bit_cast(float, u);
}
__device__ __forceinline__ float sigm(float x) {
  x = fminf(fmaxf(x, -30.f), 30.f);
  return 1.f / (1.f + __expf(-x));
}
__device__ __forceinline__ float tanh_fast(float x) {
  x = fminf(fmaxf(x, -15.f), 15.f);
  float e = __expf(2.f * x);
  return (e - 1.f) / (e + 1.f);
}

// LLC-coherent (L2-bypass) ops for the cross-XCD ring.
__device__ __forceinline__ void llc_load32(const float* p, f32x4& a, f32x4& b) {
  asm volatile("global_load_dwordx4 %0, %2, off sc0 sc1\n\t"
               "global_load_dwordx4 %1, %3, off sc0 sc1\n\t"
               "s_waitcnt vmcnt(0)"
               : "=&v"(a), "=&v"(b)
               : "v"(p), "v"(p + 4)
               : "memory");
}
__device__ __forceinline__ void llc_store16(float* p, f32x4 v) {
  asm volatile("global_store_dwordx4 %0, %1, off sc0 sc1"
               :: "v"(p), "v"(v) : "memory");
}

// ---------------------------------------------------------------------------
// prep: wp1 = fused [Wr | Wz] (896 x 416) in MFMA A-frag order;
//       wp2 = [WU' | Wij] (128 x 416), rows permuted within each 16-tile
//       (WU row 4(f&3)+(f>>2) at frag slot f) so GEMM2 output lanes align
//       with GEMM1's z-lane (u,bl) mapping; bfused; progress flags.
// ---------------------------------------------------------------------------
__global__ void prep_kernel(const float* __restrict__ Wr, const float* __restrict__ Wz,
                            const float* __restrict__ Wij, const float* __restrict__ WU,
                            const float* __restrict__ br, const float* __restrict__ bz,
                            const float* __restrict__ bij,
                            unsigned short* __restrict__ wp1, unsigned short* __restrict__ wp2,
                            float* __restrict__ bfused) {
  int blk = blockIdx.x, lane = threadIdx.x;
  if (blk < 728) {                       // 13 kb * 56 ntiles for W' (n<896)
    int kb = blk / 56, nt = blk % 56;
    int n = nt * 16 + (lane & 15);
    int kb8 = kb * 32 + (lane >> 4) * 8;
    unsigned short v[8];
#pragma unroll
    for (int j = 0; j < 8; ++j) {
      int k = kb8 + j; float w;
      if (n < 384) w = Wr[n * 416 + k];
      else { int u = (n - 384) >> 2, g = (n - 384) & 3; w = Wz[(g * 128 + u) * 416 + k]; }
      v[j] = f2bf(w);
    }
    ushort4v* dst = (ushort4v*)(wp1 + ((size_t)(kb * 56 + nt) * 64 + lane) * 8);
    dst[0] = (ushort4v){v[0], v[1], v[2], v[3]};
    dst[1] = (ushort4v){v[4], v[5], v[6], v[7]};
  } else if (blk < 728 + 104) {          // 13 kb * 8 ntiles for [WU' | Wij]
    int b2 = blk - 728;
    int kb = b2 >> 3, nt = b2 & 7;
    int f = lane & 15;
    int u = nt * 16 + ((f & 3) * 4) + (f >> 2);   // row permutation
    int kb8 = kb * 32 + (lane >> 4) * 8;
    unsigned short v[8];
#pragma unroll
    for (int j = 0; j < 8; ++j) {
      int c = kb8 + j; float w;
      if (c < 384) {
        int s = (c < 128) ? c + 128 : (c < 256 ? c - 128 : c);  // hl,ht,hd -> ht,hl,hd
        w = WU[u * 384 + s];
      } else {
        w = Wij[u * 32 + (c - 384)];
      }
      v[j] = f2bf(w);
    }
    ushort4v* dst = (ushort4v*)(wp2 + ((size_t)(kb * 8 + nt) * 64 + lane) * 8);
    dst[0] = (ushort4v){v[0], v[1], v[2], v[3]};
    dst[1] = (ushort4v){v[4], v[5], v[6], v[7]};
  } else if (blk == 832) {               // fused bias (1024 fp32)
#pragma unroll
    for (int i = 0; i < 16; ++i) {
      int n = lane * 16 + i; float v;
      if (n < 384) v = br[n];
      else if (n < 896) { int u = (n - 384) >> 2, g = (n - 384) & 3; v = bz[g * 128 + u]; }
      else v = bij[n - 896];
      bfused[n] = v;
    }
  } else {                               // zero progress flags
    for (int i = lane; i < 160; i += 64)
      __hip_atomic_store(&g_progress[i], 0, __ATOMIC_RELAXED, __HIP_MEMORY_SCOPE_AGENT);
  }
}

// one GEMM1 K-step (16 MFMA over the wave's 64n x 64b tile), weights from L2
#define G1_STEP(KB)                                                                        \
  {                                                                                        \
    bf16x8 wf[4], qf[4];                                                                   \
    _Pragma("unroll")                                                                      \
    for (int mt = 0; mt < 4; ++mt)                                                         \
      wf[mt] = *(const bf16x8*)(wp1 + ((size_t)((KB) * 56 + ntb + mt) * 64 + lane) * 8);   \
    _Pragma("unroll")                                                                      \
    for (int bt = 0; bt < 4; ++bt)                                                         \
      qf[bt] = *(const bf16x8*)(lds + (size_t)(bt * 16 + l15) * QPITCH + (KB) * 32 + quad * 8); \
    _Pragma("unroll")                                                                      \
    for (int mt = 0; mt < 4; ++mt)                                                         \
      _Pragma("unroll")                                                                    \
      for (int bt = 0; bt < 4; ++bt)                                                       \
        acc[mt][bt] = __builtin_amdgcn_mfma_f32_16x16x32_bf16(wf[mt], qf[bt], acc[mt][bt], 0, 0, 0); \
  }

// ---------------------------------------------------------------------------
// Persistent wavefront kernel. LDS (155,648 B):
//   q bf16 [64][QPITCH]     @ 0       cols: ht(0..127)|hl(128..255)|hd|x
//   htopF fp32 [64][HPITCH] @ 54,272  own h(l-1), relay source for ring
//   hlD0/hlD1 fp32          @ 88,064 / 121,856   h_left double buffer
// ---------------------------------------------------------------------------
__global__ __launch_bounds__(1024)
void gru_persist(const float* __restrict__ x, const float* __restrict__ bfused,
                 const unsigned short* __restrict__ wp1, const unsigned short* __restrict__ wp2,
                 float* __restrict__ ring,
                 unsigned short* __restrict__ xp,   // nullable: per-block [80][2048] bf16
                 float* __restrict__ out) {
  const int blk = blockIdx.x;
  const int rc = (blk < 80) ? blk : blk - 80;
  const int bh = (blk < 80) ? 0 : 1;
  const int tid = threadIdx.x;
  const int wave = tid >> 6, lane = tid & 63;
  const int quad = lane >> 4, l15 = lane & 15;
  const int i2 = tid * 2;                        // (b_local, c) pair id
  const int bb = i2 >> 5, cc = i2 & 31;

  extern __shared__ char smem[];
  unsigned short* lds = (unsigned short*)smem;
  float* htopF = (float*)(smem + 54272);
  float* hlD0  = (float*)(smem + 88064);
  float* hlD1  = (float*)(smem + 121856);

  float* ringMine = ring + (size_t)blk * 24576;  // 3 slots x 8192 fp32
  unsigned short* xpB = xp ? (xp + (size_t)blk * 163840) : nullptr;

  // ---- init: zero h buffers + q cols 0..383 ----
  for (int i = tid; i < 64 * HPITCH; i += 1024) { htopF[i] = 0.f; hlD0[i] = 0.f; hlD1[i] = 0.f; }
  {
    int r = tid >> 4, c0 = (tid & 15) * 24;      // 64 rows x 384 cols
#pragma unroll
    for (int j = 0; j < 6; ++j)
      *(ushort4v*)(lds + (size_t)r * QPITCH + c0 + j * 4) = (ushort4v){0, 0, 0, 0};
  }
  // ---- x: one-time private transpose into xp (contiguous per l) ----
  if (xpB) {
    const float* xb = x + (size_t)(bh * 2048 + i2) * 6400 + rc;
#pragma unroll 4
    for (int l = 0; l < 80; ++l) {
      float v0 = __builtin_nontemporal_load(xb + l * 80);
      float v1 = __builtin_nontemporal_load(xb + 6400 + l * 80);
      ushort2v o = (ushort2v){f2bf(v0), f2bf(v1)};
      __builtin_nontemporal_store(__builtin_bit_cast(unsigned int, o),
                                  (unsigned int*)(xpB + (size_t)l * 2048 + i2));
      if (l == 0)
        *(ushort2v*)(lds + (size_t)bb * QPITCH + 384 + cc) = o;
    }
  } else {
    const float* xb = x + rc;
    float v0 = __builtin_nontemporal_load(xb + (size_t)(bh * 2048 + i2) * 6400);
    float v1 = __builtin_nontemporal_load(xb + (size_t)(bh * 2048 + i2 + 1) * 6400);
    *(ushort2v*)(lds + (size_t)bb * QPITCH + 384 + cc) = (ushort2v){f2bf(v0), f2bf(v1)};
  }
  __syncthreads();

  const int ntb = wave * 4;                      // GEMM1 n-tile base (waves 0..13)
  const int jz = wave - 6;                       // z-wave id 0..7 (waves 6..13)
  const bool isOut = (rc == 79);                 // block-uniform

  // loop-invariant biases (may remat under pressure; correct either way)
  f32x4 biasv[4];
#pragma unroll
  for (int mt = 0; mt < 4; ++mt)
    biasv[mt] = *(const f32x4*)(bfused + ((wave < 14 ? wave : 0) * 64) + mt * 16 + quad * 4);
  float bij_r[4];
#pragma unroll
  for (int mt = 0; mt < 4; ++mt)
    bij_r[mt] = (wave >= 6 && wave < 14) ? bfused[896 + 16 * jz + 4 * mt + quad] : 0.f;

  float hz_r[4][4], zi_r[4][4];                  // z-wave state across phases

  for (int l = 0; l < 80; ++l) {
    // ---- x prefetch for l+1 (nt; hidden under part A) ----
    unsigned int xn = 0;
    if (l < 79) {
      if (xpB) {
        xn = __builtin_nontemporal_load((const unsigned int*)(xpB + (size_t)(l + 1) * 2048 + i2));
      } else {
        const float* xb = x + (size_t)(l + 1) * 80 + rc;
        float v0 = __builtin_nontemporal_load(xb + (size_t)(bh * 2048 + i2) * 6400);
        float v1 = __builtin_nontemporal_load(xb + (size_t)(bh * 2048 + i2 + 1) * 6400);
        xn = __builtin_bit_cast(unsigned int, (ushort2v){f2bf(v0), f2bf(v1)});
      }
    }

    // ---- GEMM1 part A: kb {0..3, 8..12} (ht, hd, x) — neighbor-free ----
    f32x4 acc[4][4];
    if (wave < 14) {
#pragma unroll
      for (int mt = 0; mt < 4; ++mt)
#pragma unroll
        for (int bt = 0; bt < 4; ++bt) acc[mt][bt] = (f32x4){0.f, 0.f, 0.f, 0.f};
#pragma unroll
      for (int t = 0; t < 9; ++t) {
        const int kb = (t < 4) ? t : t + 4;
        G1_STEP(kb)
      }
    }

    // ---- spin (single lane, BOUNDED): left done row l; right freed slot ----
    // Guard ~45ms/wait (legit waits are us): a protocol wedge self-terminates
    // into a wrong-answer run with counters instead of a dead container.
    if (tid == 0) {
      if (rc > 0) {
        int guard = 0;
        while (__hip_atomic_load(&g_progress[blk - 1], __ATOMIC_RELAXED, __HIP_MEMORY_SCOPE_AGENT) < l + 1
               && guard < 1600000) { __builtin_amdgcn_s_sleep(2); ++guard; }
      }
      if (rc < 79) {
        int guard = 0;
        while (__hip_atomic_load(&g_progress[blk + 1], __ATOMIC_RELAXED, __HIP_MEMORY_SCOPE_AGENT) < l - 2
               && guard < 1600000) { __builtin_amdgcn_s_sleep(2); ++guard; }
      }
    }
    asm volatile("" ::: "memory");
    __syncthreads();                                             // B1

    // ---- stage B: h_left from neighbor ring (LLC dwordx4) ----
    if (rc > 0) {
      const float* src = ring + (size_t)(blk - 1) * 24576 + (size_t)(l % 3) * 8192 + tid * 8;
      f32x4 a, b;
      llc_load32(src, a, b);
      int bl = (tid * 8) >> 7, u = (tid * 8) & 127;
      float* hlF = (l & 1) ? hlD1 : hlD0;
      *(f32x4*)(hlF + bl * HPITCH + u)     = a;
      *(f32x4*)(hlF + bl * HPITCH + u + 4) = b;
      *(ushort4v*)(lds + (size_t)bl * QPITCH + 128 + u)     = (ushort4v){f2bf(a[0]), f2bf(a[1]), f2bf(a[2]), f2bf(a[3])};
      *(ushort4v*)(lds + (size_t)bl * QPITCH + 128 + u + 4) = (ushort4v){f2bf(b[0]), f2bf(b[1]), f2bf(b[2]), f2bf(b[3])};
    }
    __syncthreads();                                             // B2

    // ---- GEMM1 part B: kb 4..7 (hl) ----
    if (wave < 14) {
#pragma unroll
      for (int kb = 4; kb < 8; ++kb) { G1_STEP(kb) }
    }
    __syncthreads();                                             // B3

    // ---- elementwise ----
    if (wave < 6) {
      // r class: sigmoid, A2' = r*q in place (shift maps r col -> q col)
      const int rn0 = wave * 64;
      const int shift = (rn0 < 128) ? 128 : (rn0 < 256 ? -128 : 0);
#pragma unroll
      for (int mt = 0; mt < 4; ++mt)
#pragma unroll
        for (int bt = 0; bt < 4; ++bt) {
          int n0 = rn0 + mt * 16 + quad * 4;
          int row = bt * 16 + l15;
          unsigned short* p = lds + (size_t)row * QPITCH + n0 + shift;
          ushort4v qv = *(ushort4v*)p;
          ushort4v o;
#pragma unroll
          for (int g = 0; g < 4; ++g) {
            float r = sigm(acc[mt][bt][g] + biasv[mt][g]);
            o[g] = f2bf(bf2f(qv[g]) * r);
          }
          *(ushort4v*)p = o;
        }
    } else if (wave < 14) {
      // z class: lane-local softmax; fold fp32 h's; keep hz/zi in registers
      const float* hlF = (l & 1) ? hlD1 : hlD0;
      const float* hdF = (l & 1) ? hlD0 : hlD1;
#pragma unroll
      for (int mt = 0; mt < 4; ++mt)
#pragma unroll
        for (int bt = 0; bt < 4; ++bt) {
          int u = 16 * jz + 4 * mt + quad;
          int bl = 16 * bt + l15;
          float v0 = acc[mt][bt][0] + biasv[mt][0];
          float v1 = acc[mt][bt][1] + biasv[mt][1];
          float v2 = acc[mt][bt][2] + biasv[mt][2];
          float v3 = acc[mt][bt][3] + biasv[mt][3];
          float m = fmaxf(fmaxf(v0, v1), fmaxf(v2, v3));
          float e0 = __expf(v0 - m), e1 = __expf(v1 - m);
          float e2 = __expf(v2 - m), e3 = __expf(v3 - m);
          float inv = 1.f / (e0 + e1 + e2 + e3);
          float hl = hlF[bl * HPITCH + u];
          float ht = htopF[bl * HPITCH + u];
          float hd = hdF[bl * HPITCH + u];
          hz_r[mt][bt] = (e1 * hl + e2 * ht + e3 * hd) * inv;  // zl,zt,zd fold
          zi_r[mt][bt] = e0 * inv;
        }
    }
    __syncthreads();                                             // B4

    // ---- GEMM2 (z-waves only): hU+cw over K=416 incl. Wij block ----
    f32x4 acc2[4];
    if (wave >= 6 && wave < 14) {
#pragma unroll
      for (int bt = 0; bt < 4; ++bt) acc2[bt] = (f32x4){0.f, 0.f, 0.f, 0.f};
#pragma unroll
      for (int kb = 0; kb < 13; ++kb) {
        bf16x8 wf = *(const bf16x8*)(wp2 + ((size_t)(kb * 8 + jz) * 64 + lane) * 8);
#pragma unroll
        for (int bt = 0; bt < 4; ++bt) {
          bf16x8 qf = *(const bf16x8*)(lds + (size_t)(bt * 16 + l15) * QPITCH + kb * 32 + quad * 8);
          acc2[bt] = __builtin_amdgcn_mfma_f32_16x16x32_bf16(wf, qf, acc2[bt], 0, 0, 0);
        }
      }
    }
    __syncthreads();                                             // B5

    // ---- combine (z-waves, in-register) ∥ stage-A (all threads) ----
    if (wave >= 6 && wave < 14) {
      // acc2[bt][g] holds u = 16*jz + 4*g + quad (row-permuted wp2) -> g==mt
#pragma unroll
      for (int mt = 0; mt < 4; ++mt)
#pragma unroll
        for (int bt = 0; bt < 4; ++bt) {
          float h = hz_r[mt][bt] + zi_r[mt][bt] * tanh_fast(acc2[bt][mt] + bij_r[mt]);
          int bl = 16 * bt + l15;
          int uu = 16 * jz + 4 * mt + quad;
          htopF[bl * HPITCH + uu] = h;                 // fp32 ht for l+1 + relay src
          lds[(size_t)bl * QPITCH + uu] = f2bf(h);     // bf16 ht col for l+1
        }
    }
    if (l < 79) {
      // hd (q cols 256..383) <- hl fp32 of this step; x col from prefetch
      const float* hdF = ((l + 1) & 1) ? hlD0 : hlD1;
      int idx = tid * 8, bl = idx >> 7, u = idx & 127;
      f32x4 a = *(const f32x4*)(hdF + bl * HPITCH + u);
      f32x4 b = *(const f32x4*)(hdF + bl * HPITCH + u + 4);
      *(ushort4v*)(lds + (size_t)bl * QPITCH + 256 + u)     = (ushort4v){f2bf(a[0]), f2bf(a[1]), f2bf(a[2]), f2bf(a[3])};
      *(ushort4v*)(lds + (size_t)bl * QPITCH + 256 + u + 4) = (ushort4v){f2bf(b[0]), f2bf(b[1]), f2bf(b[2]), f2bf(b[3])};
      *(ushort2v*)(lds + (size_t)bb * QPITCH + 384 + cc) = __builtin_bit_cast(ushort2v, xn);
    }
    __syncthreads();                                             // B6

    // ---- relay publish: coalesced LLC stores of h(l) from htopF ----
    {
      int idx = tid * 8, bl = idx >> 7, u = idx & 127;
      f32x4 a = *(const f32x4*)(htopF + bl * HPITCH + u);
      f32x4 b = *(const f32x4*)(htopF + bl * HPITCH + u + 4);
      float* dst = ringMine + (size_t)(l % 3) * 8192 + idx;
      llc_store16(dst, a);
      llc_store16(dst + 4, b);
      if (isOut && l == 79) {
        *(f32x4*)(out + (size_t)(bh * 8192) + idx)     = a;
        *(f32x4*)(out + (size_t)(bh * 8192) + idx + 4) = b;
      }
      asm volatile("s_waitcnt vmcnt(0)" ::: "memory");
    }
    __syncthreads();                                             // B7 (stores drained)
    if (tid == 0)
      __hip_atomic_store(&g_progress[blk], l + 1, __ATOMIC_RELAXED, __HIP_MEMORY_SCOPE_AGENT);
  }
}

// ---------------------------------------------------------------------------
extern "C" void kernel_launch(void* const* d_in, const int* in_sizes, int n_in,
                              void* d_out, int out_size, void* d_ws, size_t ws_size,
                              hipStream_t stream) {
  const float* x   = (const float*)d_in[0];
  const float* Wr  = (const float*)d_in[1];
  const float* br  = (const float*)d_in[2];
  const float* Wz  = (const float*)d_in[3];
  const float* bz  = (const float*)d_in[4];
  const float* Wij = (const float*)d_in[5];
  const float* bij = (const float*)d_in[6];
  const float* WU  = (const float*)d_in[7];
  float* out = (float*)d_out;

  // ws layout: wp1 | wp2 | bfused | ring | xp   (scratch eliminated)
  char* ws = (char*)d_ws;
  unsigned short* wp1 = (unsigned short*)(ws);                 //    745,472 B
  unsigned short* wp2 = (unsigned short*)(ws + 745472);        //    106,496 B
  float* bfused       = (float*)(ws + 851968);                 //      4,096 B
  float* ring         = (float*)(ws + 856064);                 // 15,728,640 B
  // xp: 160 blocks x 80 l x 2048 bf16 = 52,428,800 B (only if ws allows)
  unsigned short* xp  = (ws_size >= 69013504ull)
                        ? (unsigned short*)(ws + 16584704) : nullptr;

  (void)hipFuncSetAttribute((const void*)gru_persist,
                            hipFuncAttributeMaxDynamicSharedMemorySize, 155648);

  prep_kernel<<<834, 64, 0, stream>>>(Wr, Wz, Wij, WU, br, bz, bij, wp1, wp2, bfused);
  gru_persist<<<160, 1024, 155648, stream>>>(x, bfused, wp1, wp2, ring, xp, out);
}

// Round 7
// 6212.707 us; speedup vs baseline: 1.4184x; 1.0530x over previous
//
#include <hip/hip_runtime.h>
#include <stdint.h>

// SpatialGRU on MI355X, round 9: minimal safe delta off round 7 (6.44ms, PASS).
// Round-7 FETCH forensics: ~3.4GB of the 5.2GB was the one-time x transpose
// (nt gathers: every 4B pulls a 128B HBM line, no cross-block dedup though 32
// rc-blocks share each line). Ring ops used sc0+sc1 = SYSTEM scope on gfx95x
// ({SC1,SC0}: sc1=agent/LLC, sc0+sc1=system/HBM) -> every handoff was an HBM
// round-trip (the unexplained WRITE_SIZE). Three changes only:
//   (1) ring ops sc0 sc1 -> sc1 (device scope, LLC-served; round-3's working
//       agent-scope atomics prove agent scope suffices cross-XCD);
//   (2) transpose gathers: drop nt (plain cached -> LLC dedup across blocks);
//   (3) spin guards 1.6M -> 200K iters (~12ms/wait; still 100x legit waits).
// Round-8's warm-touch + reg-pinning dropped pending clean measurement.

typedef __bf16 bf16x8 __attribute__((ext_vector_type(8)));
typedef float  f32x4  __attribute__((ext_vector_type(4)));
typedef unsigned short ushort4v __attribute__((ext_vector_type(4)));
typedef unsigned short ushort2v __attribute__((ext_vector_type(2)));

#define QPITCH 424   // 416 q cols + 8 pad (bf16 elems)
#define HPITCH 132   // fp32 h rows padded +4

__device__ int g_progress[160];   // cells completed per block

__device__ __forceinline__ unsigned short f2bf(float x) {
  unsigned int u = __builtin_bit_cast(unsigned int, x);
  u = u + 0x7FFFu + ((u >> 16) & 1u);          // round-to-nearest-even
  return (unsigned short)(u >> 16);
}
__device__ __forceinline__ float bf2f(unsigned short h) {
  unsigned int u = ((unsigned int)h) << 16;
  return __builtin_bit_cast(float, u);
}
__device__ __forceinline__ float sigm(float x) {
  x = fminf(fmaxf(x, -30.f), 30.f);
  return 1.f / (1.f + __expf(-x));
}
__device__ __forceinline__ float tanh_fast(float x) {
  x = fminf(fmaxf(x, -15.f), 15.f);
  float e = __expf(2.f * x);
  return (e - 1.f) / (e + 1.f);
}

// Device-scope (LLC-coherent, LLC-served) ops for the cross-XCD ring.
// sc1 = agent/device scope on gfx94x/950; sc0+sc1 (system) forces HBM.
__device__ __forceinline__ void llc_load32(const float* p, f32x4& a, f32x4& b) {
  asm volatile("global_load_dwordx4 %0, %2, off sc1\n\t"
               "global_load_dwordx4 %1, %3, off sc1\n\t"
               "s_waitcnt vmcnt(0)"
               : "=&v"(a), "=&v"(b)
               : "v"(p), "v"(p + 4)
               : "memory");
}
__device__ __forceinline__ void llc_store16(float* p, f32x4 v) {
  asm volatile("global_store_dwordx4 %0, %1, off sc1"
               :: "v"(p), "v"(v) : "memory");
}

// ---------------------------------------------------------------------------
// prep: wp1 = fused [Wr | Wz] (896 x 416) in MFMA A-frag order;
//       wp2 = [WU' | Wij] (128 x 416), rows permuted within each 16-tile
//       (WU row 4(f&3)+(f>>2) at frag slot f) so GEMM2 output lanes align
//       with GEMM1's z-lane (u,bl) mapping; bfused; progress flags.
// ---------------------------------------------------------------------------
__global__ void prep_kernel(const float* __restrict__ Wr, const float* __restrict__ Wz,
                            const float* __restrict__ Wij, const float* __restrict__ WU,
                            const float* __restrict__ br, const float* __restrict__ bz,
                            const float* __restrict__ bij,
                            unsigned short* __restrict__ wp1, unsigned short* __restrict__ wp2,
                            float* __restrict__ bfused) {
  int blk = blockIdx.x, lane = threadIdx.x;
  if (blk < 728) {                       // 13 kb * 56 ntiles for W' (n<896)
    int kb = blk / 56, nt = blk % 56;
    int n = nt * 16 + (lane & 15);
    int kb8 = kb * 32 + (lane >> 4) * 8;
    unsigned short v[8];
#pragma unroll
    for (int j = 0; j < 8; ++j) {
      int k = kb8 + j; float w;
      if (n < 384) w = Wr[n * 416 + k];
      else { int u = (n - 384) >> 2, g = (n - 384) & 3; w = Wz[(g * 128 + u) * 416 + k]; }
      v[j] = f2bf(w);
    }
    ushort4v* dst = (ushort4v*)(wp1 + ((size_t)(kb * 56 + nt) * 64 + lane) * 8);
    dst[0] = (ushort4v){v[0], v[1], v[2], v[3]};
    dst[1] = (ushort4v){v[4], v[5], v[6], v[7]};
  } else if (blk < 728 + 104) {          // 13 kb * 8 ntiles for [WU' | Wij]
    int b2 = blk - 728;
    int kb = b2 >> 3, nt = b2 & 7;
    int f = lane & 15;
    int u = nt * 16 + ((f & 3) * 4) + (f >> 2);   // row permutation
    int kb8 = kb * 32 + (lane >> 4) * 8;
    unsigned short v[8];
#pragma unroll
    for (int j = 0; j < 8; ++j) {
      int c = kb8 + j; float w;
      if (c < 384) {
        int s = (c < 128) ? c + 128 : (c < 256 ? c - 128 : c);  // hl,ht,hd -> ht,hl,hd
        w = WU[u * 384 + s];
      } else {
        w = Wij[u * 32 + (c - 384)];
      }
      v[j] = f2bf(w);
    }
    ushort4v* dst = (ushort4v*)(wp2 + ((size_t)(kb * 8 + nt) * 64 + lane) * 8);
    dst[0] = (ushort4v){v[0], v[1], v[2], v[3]};
    dst[1] = (ushort4v){v[4], v[5], v[6], v[7]};
  } else if (blk == 832) {               // fused bias (1024 fp32)
#pragma unroll
    for (int i = 0; i < 16; ++i) {
      int n = lane * 16 + i; float v;
      if (n < 384) v = br[n];
      else if (n < 896) { int u = (n - 384) >> 2, g = (n - 384) & 3; v = bz[g * 128 + u]; }
      else v = bij[n - 896];
      bfused[n] = v;
    }
  } else {                               // zero progress flags
    for (int i = lane; i < 160; i += 64)
      __hip_atomic_store(&g_progress[i], 0, __ATOMIC_RELAXED, __HIP_MEMORY_SCOPE_AGENT);
  }
}

// one GEMM1 K-step (16 MFMA over the wave's 64n x 64b tile), weights from L2
#define G1_STEP(KB)                                                                        \
  {                                                                                        \
    bf16x8 wf[4], qf[4];                                                                   \
    _Pragma("unroll")                                                                      \
    for (int mt = 0; mt < 4; ++mt)                                                         \
      wf[mt] = *(const bf16x8*)(wp1 + ((size_t)((KB) * 56 + ntb + mt) * 64 + lane) * 8);   \
    _Pragma("unroll")                                                                      \
    for (int bt = 0; bt < 4; ++bt)                                                         \
      qf[bt] = *(const bf16x8*)(lds + (size_t)(bt * 16 + l15) * QPITCH + (KB) * 32 + quad * 8); \
    _Pragma("unroll")                                                                      \
    for (int mt = 0; mt < 4; ++mt)                                                         \
      _Pragma("unroll")                                                                    \
      for (int bt = 0; bt < 4; ++bt)                                                       \
        acc[mt][bt] = __builtin_amdgcn_mfma_f32_16x16x32_bf16(wf[mt], qf[bt], acc[mt][bt], 0, 0, 0); \
  }

// ---------------------------------------------------------------------------
// Persistent wavefront kernel. LDS (155,648 B):
//   q bf16 [64][QPITCH]     @ 0       cols: ht(0..127)|hl(128..255)|hd|x
//   htopF fp32 [64][HPITCH] @ 54,272  own h(l-1), relay source for ring
//   hlD0/hlD1 fp32          @ 88,064 / 121,856   h_left double buffer
// ---------------------------------------------------------------------------
__global__ __launch_bounds__(1024)
void gru_persist(const float* __restrict__ x, const float* __restrict__ bfused,
                 const unsigned short* __restrict__ wp1, const unsigned short* __restrict__ wp2,
                 float* __restrict__ ring,
                 unsigned short* __restrict__ xp,   // nullable: per-block [80][2048] bf16
                 float* __restrict__ out) {
  const int blk = blockIdx.x;
  const int rc = (blk < 80) ? blk : blk - 80;
  const int bh = (blk < 80) ? 0 : 1;
  const int tid = threadIdx.x;
  const int wave = tid >> 6, lane = tid & 63;
  const int quad = lane >> 4, l15 = lane & 15;
  const int i2 = tid * 2;                        // (b_local, c) pair id
  const int bb = i2 >> 5, cc = i2 & 31;

  extern __shared__ char smem[];
  unsigned short* lds = (unsigned short*)smem;
  float* htopF = (float*)(smem + 54272);
  float* hlD0  = (float*)(smem + 88064);
  float* hlD1  = (float*)(smem + 121856);

  float* ringMine = ring + (size_t)blk * 24576;  // 3 slots x 8192 fp32
  unsigned short* xpB = xp ? (xp + (size_t)blk * 163840) : nullptr;

  // ---- init: zero h buffers + q cols 0..383 ----
  for (int i = tid; i < 64 * HPITCH; i += 1024) { htopF[i] = 0.f; hlD0[i] = 0.f; hlD1[i] = 0.f; }
  {
    int r = tid >> 4, c0 = (tid & 15) * 24;      // 64 rows x 384 cols
#pragma unroll
    for (int j = 0; j < 6; ++j)
      *(ushort4v*)(lds + (size_t)r * QPITCH + c0 + j * 4) = (ushort4v){0, 0, 0, 0};
  }
  // ---- x: one-time private transpose into xp. Gathers are PLAIN cached
  // loads now: 32 rc-blocks share every 128B line -> LLC/L2 dedup (the nt
  // version re-fetched each line from HBM per block: ~3.4GB, ~0.5ms). ----
  if (xpB) {
    const float* xb = x + (size_t)(bh * 2048 + i2) * 6400 + rc;
#pragma unroll 4
    for (int l = 0; l < 80; ++l) {
      float v0 = xb[l * 80];
      float v1 = xb[6400 + l * 80];
      ushort2v o = (ushort2v){f2bf(v0), f2bf(v1)};
      __builtin_nontemporal_store(__builtin_bit_cast(unsigned int, o),
                                  (unsigned int*)(xpB + (size_t)l * 2048 + i2));
      if (l == 0)
        *(ushort2v*)(lds + (size_t)bb * QPITCH + 384 + cc) = o;
    }
  } else {
    const float* xb = x + rc;
    float v0 = xb[(size_t)(bh * 2048 + i2) * 6400];
    float v1 = xb[(size_t)(bh * 2048 + i2 + 1) * 6400];
    *(ushort2v*)(lds + (size_t)bb * QPITCH + 384 + cc) = (ushort2v){f2bf(v0), f2bf(v1)};
  }
  __syncthreads();

  const int ntb = wave * 4;                      // GEMM1 n-tile base (waves 0..13)
  const int jz = wave - 6;                       // z-wave id 0..7 (waves 6..13)
  const bool isOut = (rc == 79);                 // block-uniform

  // loop-invariant biases (may remat under pressure; correct either way)
  f32x4 biasv[4];
#pragma unroll
  for (int mt = 0; mt < 4; ++mt)
    biasv[mt] = *(const f32x4*)(bfused + ((wave < 14 ? wave : 0) * 64) + mt * 16 + quad * 4);
  float bij_r[4];
#pragma unroll
  for (int mt = 0; mt < 4; ++mt)
    bij_r[mt] = (wave >= 6 && wave < 14) ? bfused[896 + 16 * jz + 4 * mt + quad] : 0.f;

  float hz_r[4][4], zi_r[4][4];                  // z-wave state across phases

  for (int l = 0; l < 80; ++l) {
    // ---- x prefetch for l+1 (nt; private, read-once; hidden under part A) ----
    unsigned int xn = 0;
    if (l < 79) {
      if (xpB) {
        xn = __builtin_nontemporal_load((const unsigned int*)(xpB + (size_t)(l + 1) * 2048 + i2));
      } else {
        const float* xb = x + (size_t)(l + 1) * 80 + rc;
        float v0 = xb[(size_t)(bh * 2048 + i2) * 6400];
        float v1 = xb[(size_t)(bh * 2048 + i2 + 1) * 6400];
        xn = __builtin_bit_cast(unsigned int, (ushort2v){f2bf(v0), f2bf(v1)});
      }
    }

    // ---- GEMM1 part A: kb {0..3, 8..12} (ht, hd, x) — neighbor-free ----
    f32x4 acc[4][4];
    if (wave < 14) {
#pragma unroll
      for (int mt = 0; mt < 4; ++mt)
#pragma unroll
        for (int bt = 0; bt < 4; ++bt) acc[mt][bt] = (f32x4){0.f, 0.f, 0.f, 0.f};
#pragma unroll
      for (int t = 0; t < 9; ++t) {
        const int kb = (t < 4) ? t : t + 4;
        G1_STEP(kb)
      }
    }

    // ---- spin (single lane, BOUNDED ~12ms/wait): left done row l;
    //      right freed slot. Guard keeps any wedge terminating. ----
    if (tid == 0) {
      if (rc > 0) {
        int guard = 0;
        while (__hip_atomic_load(&g_progress[blk - 1], __ATOMIC_RELAXED, __HIP_MEMORY_SCOPE_AGENT) < l + 1
               && guard < 200000) { __builtin_amdgcn_s_sleep(2); ++guard; }
      }
      if (rc < 79) {
        int guard = 0;
        while (__hip_atomic_load(&g_progress[blk + 1], __ATOMIC_RELAXED, __HIP_MEMORY_SCOPE_AGENT) < l - 2
               && guard < 200000) { __builtin_amdgcn_s_sleep(2); ++guard; }
      }
    }
    asm volatile("" ::: "memory");
    __syncthreads();                                             // B1

    // ---- stage B: h_left from neighbor ring (device-scope dwordx4) ----
    if (rc > 0) {
      const float* src = ring + (size_t)(blk - 1) * 24576 + (size_t)(l % 3) * 8192 + tid * 8;
      f32x4 a, b;
      llc_load32(src, a, b);
      int bl = (tid * 8) >> 7, u = (tid * 8) & 127;
      float* hlF = (l & 1) ? hlD1 : hlD0;
      *(f32x4*)(hlF + bl * HPITCH + u)     = a;
      *(f32x4*)(hlF + bl * HPITCH + u + 4) = b;
      *(ushort4v*)(lds + (size_t)bl * QPITCH + 128 + u)     = (ushort4v){f2bf(a[0]), f2bf(a[1]), f2bf(a[2]), f2bf(a[3])};
      *(ushort4v*)(lds + (size_t)bl * QPITCH + 128 + u + 4) = (ushort4v){f2bf(b[0]), f2bf(b[1]), f2bf(b[2]), f2bf(b[3])};
    }
    __syncthreads();                                             // B2

    // ---- GEMM1 part B: kb 4..7 (hl) ----
    if (wave < 14) {
#pragma unroll
      for (int kb = 4; kb < 8; ++kb) { G1_STEP(kb) }
    }
    __syncthreads();                                             // B3

    // ---- elementwise ----
    if (wave < 6) {
      // r class: sigmoid, A2' = r*q in place (shift maps r col -> q col)
      const int rn0 = wave * 64;
      const int shift = (rn0 < 128) ? 128 : (rn0 < 256 ? -128 : 0);
#pragma unroll
      for (int mt = 0; mt < 4; ++mt)
#pragma unroll
        for (int bt = 0; bt < 4; ++bt) {
          int n0 = rn0 + mt * 16 + quad * 4;
          int row = bt * 16 + l15;
          unsigned short* p = lds + (size_t)row * QPITCH + n0 + shift;
          ushort4v qv = *(ushort4v*)p;
          ushort4v o;
#pragma unroll
          for (int g = 0; g < 4; ++g) {
            float r = sigm(acc[mt][bt][g] + biasv[mt][g]);
            o[g] = f2bf(bf2f(qv[g]) * r);
          }
          *(ushort4v*)p = o;
        }
    } else if (wave < 14) {
      // z class: lane-local softmax; fold fp32 h's; keep hz/zi in registers
      const float* hlF = (l & 1) ? hlD1 : hlD0;
      const float* hdF = (l & 1) ? hlD0 : hlD1;
#pragma unroll
      for (int mt = 0; mt < 4; ++mt)
#pragma unroll
        for (int bt = 0; bt < 4; ++bt) {
          int u = 16 * jz + 4 * mt + quad;
          int bl = 16 * bt + l15;
          float v0 = acc[mt][bt][0] + biasv[mt][0];
          float v1 = acc[mt][bt][1] + biasv[mt][1];
          float v2 = acc[mt][bt][2] + biasv[mt][2];
          float v3 = acc[mt][bt][3] + biasv[mt][3];
          float m = fmaxf(fmaxf(v0, v1), fmaxf(v2, v3));
          float e0 = __expf(v0 - m), e1 = __expf(v1 - m);
          float e2 = __expf(v2 - m), e3 = __expf(v3 - m);
          float inv = 1.f / (e0 + e1 + e2 + e3);
          float hl = hlF[bl * HPITCH + u];
          float ht = htopF[bl * HPITCH + u];
          float hd = hdF[bl * HPITCH + u];
          hz_r[mt][bt] = (e1 * hl + e2 * ht + e3 * hd) * inv;  // zl,zt,zd fold
          zi_r[mt][bt] = e0 * inv;
        }
    }
    __syncthreads();                                             // B4

    // ---- GEMM2 (z-waves only): hU+cw over K=416 incl. Wij block ----
    f32x4 acc2[4];
    if (wave >= 6 && wave < 14) {
#pragma unroll
      for (int bt = 0; bt < 4; ++bt) acc2[bt] = (f32x4){0.f, 0.f, 0.f, 0.f};
#pragma unroll
      for (int kb = 0; kb < 13; ++kb) {
        bf16x8 wf = *(const bf16x8*)(wp2 + ((size_t)(kb * 8 + jz) * 64 + lane) * 8);
#pragma unroll
        for (int bt = 0; bt < 4; ++bt) {
          bf16x8 qf = *(const bf16x8*)(lds + (size_t)(bt * 16 + l15) * QPITCH + kb * 32 + quad * 8);
          acc2[bt] = __builtin_amdgcn_mfma_f32_16x16x32_bf16(wf, qf, acc2[bt], 0, 0, 0);
        }
      }
    }
    __syncthreads();                                             // B5

    // ---- combine (z-waves, in-register) ∥ stage-A (all threads) ----
    if (wave >= 6 && wave < 14) {
      // acc2[bt][g] holds u = 16*jz + 4*g + quad (row-permuted wp2) -> g==mt
#pragma unroll
      for (int mt = 0; mt < 4; ++mt)
#pragma unroll
        for (int bt = 0; bt < 4; ++bt) {
          float h = hz_r[mt][bt] + zi_r[mt][bt] * tanh_fast(acc2[bt][mt] + bij_r[mt]);
          int bl = 16 * bt + l15;
          int uu = 16 * jz + 4 * mt + quad;
          htopF[bl * HPITCH + uu] = h;                 // fp32 ht for l+1 + relay src
          lds[(size_t)bl * QPITCH + uu] = f2bf(h);     // bf16 ht col for l+1
        }
    }
    if (l < 79) {
      // hd (q cols 256..383) <- hl fp32 of this step; x col from prefetch
      const float* hdF = ((l + 1) & 1) ? hlD0 : hlD1;
      int idx = tid * 8, bl = idx >> 7, u = idx & 127;
      f32x4 a = *(const f32x4*)(hdF + bl * HPITCH + u);
      f32x4 b = *(const f32x4*)(hdF + bl * HPITCH + u + 4);
      *(ushort4v*)(lds + (size_t)bl * QPITCH + 256 + u)     = (ushort4v){f2bf(a[0]), f2bf(a[1]), f2bf(a[2]), f2bf(a[3])};
      *(ushort4v*)(lds + (size_t)bl * QPITCH + 256 + u + 4) = (ushort4v){f2bf(b[0]), f2bf(b[1]), f2bf(b[2]), f2bf(b[3])};
      *(ushort2v*)(lds + (size_t)bb * QPITCH + 384 + cc) = __builtin_bit_cast(ushort2v, xn);
    }
    __syncthreads();                                             // B6

    // ---- relay publish: coalesced device-scope stores of h(l) ----
    {
      int idx = tid * 8, bl = idx >> 7, u = idx & 127;
      f32x4 a = *(const f32x4*)(htopF + bl * HPITCH + u);
      f32x4 b = *(const f32x4*)(htopF + bl * HPITCH + u + 4);
      float* dst = ringMine + (size_t)(l % 3) * 8192 + idx;
      llc_store16(dst, a);
      llc_store16(dst + 4, b);
      if (isOut && l == 79) {
        *(f32x4*)(out + (size_t)(bh * 8192) + idx)     = a;
        *(f32x4*)(out + (size_t)(bh * 8192) + idx + 4) = b;
      }
      asm volatile("s_waitcnt vmcnt(0)" ::: "memory");
    }
    __syncthreads();                                             // B7 (stores drained)
    if (tid == 0)
      __hip_atomic_store(&g_progress[blk], l + 1, __ATOMIC_RELAXED, __HIP_MEMORY_SCOPE_AGENT);
  }
}

// ---------------------------------------------------------------------------
extern "C" void kernel_launch(void* const* d_in, const int* in_sizes, int n_in,
                              void* d_out, int out_size, void* d_ws, size_t ws_size,
                              hipStream_t stream) {
  const float* x   = (const float*)d_in[0];
  const float* Wr  = (const float*)d_in[1];
  const float* br  = (const float*)d_in[2];
  const float* Wz  = (const float*)d_in[3];
  const float* bz  = (const float*)d_in[4];
  const float* Wij = (const float*)d_in[5];
  const float* bij = (const float*)d_in[6];
  const float* WU  = (const float*)d_in[7];
  float* out = (float*)d_out;

  // ws layout: wp1 | wp2 | bfused | ring | xp   (scratch eliminated)
  char* ws = (char*)d_ws;
  unsigned short* wp1 = (unsigned short*)(ws);                 //    745,472 B
  unsigned short* wp2 = (unsigned short*)(ws + 745472);        //    106,496 B
  float* bfused       = (float*)(ws + 851968);                 //      4,096 B
  float* ring         = (float*)(ws + 856064);                 // 15,728,640 B
  // xp: 160 blocks x 80 l x 2048 bf16 = 52,428,800 B (only if ws allows)
  unsigned short* xp  = (ws_size >= 69013504ull)
                        ? (unsigned short*)(ws + 16584704) : nullptr;

  (void)hipFuncSetAttribute((const void*)gru_persist,
                            hipFuncAttributeMaxDynamicSharedMemorySize, 155648);

  prep_kernel<<<834, 64, 0, stream>>>(Wr, Wz, Wij, WU, br, bz, bij, wp1, wp2, bfused);
  gru_persist<<<160, 1024, 155648, stream>>>(x, bfused, wp1, wp2, ring, xp, out);
}